// Round 1
// baseline (1995.130 us; speedup 1.0000x reference)
//
#include <hip/hip_runtime.h>

// Fully-fused RNN: dense encoders + 576-step LSTM + output projection + softmax.
// grid = 512 blocks (2 batch elements each), block = 256 threads.
// W_h held weight-stationary in VGPRs (100 regs per owned column, 2 cols/thread).
// h/c/act exchanged through LDS with per-step __syncthreads (block-local only).

#define NTHR 256

struct __align__(16) SM {
  float h_buf[2][2][104];   // [phase][batch][k]  double-buffered hidden state
  float woutT[9][104];      // [od][k] transposed W_out
  float s_buf[2][2][12];    // [phase][batch][f]  double-buffered encoded input
  float wx[9 * 400];        // W_x row-major
  float bl[400];            // b_lstm
  float act[2][400];        // post-activation gates per batch
  float w_in[81];
  float w_task[81];
  float b_in[9];
  float b_task[9];
  float b_out[9];
};

__global__ __launch_bounds__(NTHR, 2)
void lstm_fused(const float* __restrict__ g_input,
                const float* __restrict__ g_task,
                const float* __restrict__ g_Win,
                const float* __restrict__ g_bin,
                const float* __restrict__ g_Wtask,
                const float* __restrict__ g_btask,
                const float* __restrict__ g_Wx,
                const float* __restrict__ g_Wh,
                const float* __restrict__ g_bl,
                const float* __restrict__ g_Wout,
                const float* __restrict__ g_bout,
                float* __restrict__ g_out)
{
  __shared__ SM L;
  const int tid = threadIdx.x;
  const int bg0 = blockIdx.x * 2;   // this block's two batch elements

  // ---- cooperative LDS fill ----
  for (int i = tid; i < 3600; i += NTHR) L.wx[i] = g_Wx[i];
  for (int i = tid; i < 400; i += NTHR)  L.bl[i] = g_bl[i];
  for (int i = tid; i < 900; i += NTHR)  L.woutT[i % 9][i / 9] = g_Wout[i];
  for (int i = tid; i < 81; i += NTHR) { L.w_in[i] = g_Win[i]; L.w_task[i] = g_Wtask[i]; }
  if (tid < 9) { L.b_in[tid] = g_bin[tid]; L.b_task[tid] = g_btask[tid]; L.b_out[tid] = g_bout[tid]; }
  for (int i = tid; i < 2 * 2 * 104; i += NTHR) ((float*)L.h_buf)[i] = 0.f;

  // ---- per-thread roles ----
  // t in [0,192):   columns {t, t+192} for both batches (dot phase)
  // t in [192,208): column {384+(t-192)}
  // t in [208,226): output projection + softmax for step t-1 (wave-3 lanes 16..33)
  // t in [226,244): stage encoded input s[t+1]        (wave-3 lanes 34..51)
  // t < 200:        gate combine role (cb, ck), c kept in a register
  int col1 = -1, col2 = -1;
  if (tid < 192) { col1 = tid; col2 = tid + 192; }
  else if (tid < 208) col1 = 384 + (tid - 192);

  float w1[100], w2[100];
  if (col1 >= 0) {
#pragma unroll
    for (int k = 0; k < 100; ++k) w1[k] = g_Wh[k * 400 + col1];
  }
  if (col2 >= 0) {
#pragma unroll
    for (int k = 0; k < 100; ++k) w2[k] = g_Wh[k * 400 + col2];
  }
  const float bl1 = (col1 >= 0) ? g_bl[col1] : 0.f;
  const float bl2 = (col2 >= 0) ? g_bl[col2] : 0.f;
  // col1 is always a sigmoid gate (cols 0..191 and 384..399); col2 may be the tanh gate.
  float a2 = 1.f, bb2 = 1.f, c2 = 0.f;
  if (col2 >= 200 && col2 < 300) { a2 = 2.f; bb2 = 2.f; c2 = -1.f; }

  const int eb = (tid - 208) / 9, od = (tid - 208) % 9;   // epilogue role
  const int sb = (tid - 226) / 9, sf = (tid - 226) % 9;   // staging role
  const int cb = tid / 100, ck = tid % 100;               // combine role
  float c_state = 0.f;

  __syncthreads();

  // ---- prologue: stage encoded s for t=0 ----
  if (tid >= 226 && tid < 244) {
    const float* src = g_input + (long)(bg0 + sb) * 512 * 9;  // t=0 always from `input`
    float acc = L.b_in[sf];
#pragma unroll
    for (int f = 0; f < 9; ++f) acc += src[f] * L.w_in[f * 9 + sf];
    L.s_buf[0][sb][sf] = fmaxf(acc, 0.f);
  }
  __syncthreads();

  // ---- main recurrence ----
  for (int t = 0; t < 576; ++t) {
    const int p = t & 1;
    if (tid < 192) {
      float z10 = bl1, z11 = bl1, z20 = bl2, z21 = bl2;
#pragma unroll
      for (int f = 0; f < 9; ++f) {
        const float s0 = L.s_buf[p][0][f];
        const float s1 = L.s_buf[p][1][f];
        const float wa = L.wx[f * 400 + col1];
        const float wb = L.wx[f * 400 + col2];
        z10 += wa * s0; z11 += wa * s1;
        z20 += wb * s0; z21 += wb * s1;
      }
#pragma unroll
      for (int k = 0; k < 100; k += 4) {
        const float4 h0 = *(const float4*)&L.h_buf[p][0][k];
        const float4 h1 = *(const float4*)&L.h_buf[p][1][k];
        z10 += w1[k] * h0.x + w1[k + 1] * h0.y + w1[k + 2] * h0.z + w1[k + 3] * h0.w;
        z11 += w1[k] * h1.x + w1[k + 1] * h1.y + w1[k + 2] * h1.z + w1[k + 3] * h1.w;
        z20 += w2[k] * h0.x + w2[k + 1] * h0.y + w2[k + 2] * h0.z + w2[k + 3] * h0.w;
        z21 += w2[k] * h1.x + w2[k + 1] * h1.y + w2[k + 2] * h1.z + w2[k + 3] * h1.w;
      }
      L.act[0][col1] = 1.f / (1.f + __expf(-z10));
      L.act[1][col1] = 1.f / (1.f + __expf(-z11));
      L.act[0][col2] = a2 / (1.f + __expf(-bb2 * z20)) + c2;
      L.act[1][col2] = a2 / (1.f + __expf(-bb2 * z21)) + c2;
    } else if (tid < 208) {
      float z10 = bl1, z11 = bl1;
#pragma unroll
      for (int f = 0; f < 9; ++f) {
        const float wa = L.wx[f * 400 + col1];
        z10 += wa * L.s_buf[p][0][f];
        z11 += wa * L.s_buf[p][1][f];
      }
#pragma unroll
      for (int k = 0; k < 100; k += 4) {
        const float4 h0 = *(const float4*)&L.h_buf[p][0][k];
        const float4 h1 = *(const float4*)&L.h_buf[p][1][k];
        z10 += w1[k] * h0.x + w1[k + 1] * h0.y + w1[k + 2] * h0.z + w1[k + 3] * h0.w;
        z11 += w1[k] * h1.x + w1[k + 1] * h1.y + w1[k + 2] * h1.z + w1[k + 3] * h1.w;
      }
      L.act[0][col1] = 1.f / (1.f + __expf(-z10));   // cols 384..399: o-gate (sigmoid)
      L.act[1][col1] = 1.f / (1.f + __expf(-z11));
    } else if (tid < 226) {
      if (t > 0) {  // output for step t-1 (h[t-1] lives in h_buf[p])
        float lg = L.b_out[od];
#pragma unroll
        for (int k = 0; k < 100; k += 4) {
          const float4 hv = *(const float4*)&L.h_buf[p][eb][k];
          const float4 wv = *(const float4*)&L.woutT[od][k];
          lg += wv.x * hv.x + wv.y * hv.y + wv.z * hv.z + wv.w * hv.w;
        }
        const int lane0 = 16 + eb * 9;
        float m = lg;
#pragma unroll
        for (int j = 0; j < 9; ++j) m = fmaxf(m, __shfl(lg, lane0 + j, 64));
        const float e = __expf(lg - m);
        float ssum = 0.f;
#pragma unroll
        for (int j = 0; j < 9; ++j) ssum += __shfl(e, lane0 + j, 64);
        g_out[((long)(bg0 + eb) * 576 + (t - 1)) * 9 + od] = e / ssum;
      }
    } else if (tid < 244) {
      const int tt = t + 1;
      if (tt < 576) {  // stage encoded input for next step
        const float* src; const float* wm; const float* bm;
        if (tt < 512) {
          src = g_input + ((long)(bg0 + sb) * 512 + tt) * 9;
          wm = L.w_in;  bm = L.b_in;
        } else {
          src = g_task + ((long)(bg0 + sb) * 64 + (tt - 512)) * 9;
          wm = L.w_task; bm = L.b_task;
        }
        float acc = bm[sf];
#pragma unroll
        for (int f = 0; f < 9; ++f) acc += src[f] * wm[f * 9 + sf];
        L.s_buf[tt & 1][sb][sf] = fmaxf(acc, 0.f);
      }
    }
    __syncthreads();
    if (tid < 200) {  // gate combine: c/h update
      const float gi = L.act[cb][ck];
      const float gf = L.act[cb][ck + 100];
      const float gg = L.act[cb][ck + 200];
      const float go = L.act[cb][ck + 300];
      c_state = gf * c_state + gi * gg;
      const float th = 2.f / (1.f + __expf(-2.f * c_state)) - 1.f;
      L.h_buf[p ^ 1][cb][ck] = go * th;
    }
    __syncthreads();
  }

  // ---- tail epilogue: output for t = 575 (h[575] in h_buf[0]) ----
  if (tid >= 208 && tid < 226) {
    float lg = L.b_out[od];
#pragma unroll
    for (int k = 0; k < 100; k += 4) {
      const float4 hv = *(const float4*)&L.h_buf[0][eb][k];
      const float4 wv = *(const float4*)&L.woutT[od][k];
      lg += wv.x * hv.x + wv.y * hv.y + wv.z * hv.z + wv.w * hv.w;
    }
    const int lane0 = 16 + eb * 9;
    float m = lg;
#pragma unroll
    for (int j = 0; j < 9; ++j) m = fmaxf(m, __shfl(lg, lane0 + j, 64));
    const float e = __expf(lg - m);
    float ssum = 0.f;
#pragma unroll
    for (int j = 0; j < 9; ++j) ssum += __shfl(e, lane0 + j, 64);
    g_out[((long)(bg0 + eb) * 576 + 575) * 9 + od] = e / ssum;
  }
}

extern "C" void kernel_launch(void* const* d_in, const int* in_sizes, int n_in,
                              void* d_out, int out_size, void* d_ws, size_t ws_size,
                              hipStream_t stream) {
  const float* input  = (const float*)d_in[0];
  const float* task   = (const float*)d_in[1];
  const float* W_in   = (const float*)d_in[2];
  const float* b_in   = (const float*)d_in[3];
  const float* W_task = (const float*)d_in[4];
  const float* b_task = (const float*)d_in[5];
  const float* W_x    = (const float*)d_in[6];
  const float* W_h    = (const float*)d_in[7];
  const float* b_lstm = (const float*)d_in[8];
  const float* W_out  = (const float*)d_in[9];
  const float* b_out  = (const float*)d_in[10];
  float* out = (float*)d_out;

  lstm_fused<<<512, NTHR, 0, stream>>>(input, task, W_in, b_in, W_task, b_task,
                                       W_x, W_h, b_lstm, W_out, b_out, out);
}

// Round 2
// 1747.944 us; speedup vs baseline: 1.1414x; 1.1414x over previous
//
#include <hip/hip_runtime.h>

// Fused RNN: encoders + 576-step LSTM + projection + softmax.
// 256 blocks x 512 threads, 4 batch elements per block, 1 block/CU.
// Dot thread owns ONE W_h column (100 VGPRs, no spill at 256-VGPR budget).
// Gate-quad layout: gates {i,f,g,o} of (k,batch) live in one 4-lane quad ->
// activation exchange via same-wave LDS (in-order DS), ONE barrier per step.

#define NTHR 512

struct __align__(16) SM {
  float h_buf[2][4][104];   // [phase][batch][k]
  float s_buf[2][4][12];    // [phase][batch][f]
  float act[100][20];       // [k][4*b+g], 80 B rows (pad breaks bank stride)
  float woutT[9][104];      // [od][k]
  float w_in[81], w_task[81];
  float b_in[9], b_task[9], b_out[9];
};

__global__ __launch_bounds__(NTHR, 1)
void lstm_fused(const float* __restrict__ g_input,
                const float* __restrict__ g_task,
                const float* __restrict__ g_Win,
                const float* __restrict__ g_bin,
                const float* __restrict__ g_Wtask,
                const float* __restrict__ g_btask,
                const float* __restrict__ g_Wx,
                const float* __restrict__ g_Wh,
                const float* __restrict__ g_bl,
                const float* __restrict__ g_Wout,
                const float* __restrict__ g_bout,
                float* __restrict__ g_out)
{
  __shared__ SM L;
  const int tid = threadIdx.x;
  const int bg0 = blockIdx.x * 4;

  // ---- cooperative LDS fill ----
  for (int i = tid; i < 900; i += NTHR) L.woutT[i % 9][i / 9] = g_Wout[i];
  for (int i = tid; i < 81; i += NTHR) { L.w_in[i] = g_Win[i]; L.w_task[i] = g_Wtask[i]; }
  if (tid < 9) { L.b_in[tid] = g_bin[tid]; L.b_task[tid] = g_btask[tid]; L.b_out[tid] = g_bout[tid]; }
  for (int i = tid; i < 2 * 4 * 104; i += NTHR) ((float*)L.h_buf)[i] = 0.f;

  // ---- dot role: col = 100*q + kcol, weights in VGPRs ----
  const int q = tid & 3, kcol = tid >> 2;
  const int col = 100 * q + kcol;
  float w[100], wx[9];
  float bl = 0.f;
  if (tid < 400) {
#pragma unroll
    for (int k = 0; k < 100; ++k) w[k] = g_Wh[k * 400 + col];
#pragma unroll
    for (int f = 0; f < 9; ++f) wx[f] = g_Wx[f * 400 + col];
    bl = g_bl[col];
  }
  // q==2 is the tanh gate: tanh(z) = 2*sigmoid(2z)-1; others sigmoid.
  const float aa = (q == 2) ? 2.f : 1.f;
  const float bb = (q == 2) ? 2.f : 1.f;
  const float cc = (q == 2) ? -1.f : 0.f;
  float c_state = 0.f;   // cell state for (batch=q, k=kcol)

  const int eb = (tid - 400) / 9, od = (tid - 400) % 9;   // epilogue: wave 6 lanes 16..51
  const int sb = (tid - 448) / 9, sf = (tid - 448) % 9;   // staging:  wave 7 lanes 0..35

  __syncthreads();

  // ---- prologue: stage encoded s for t=0 ----
  if (tid >= 448 && tid < 484) {
    const float* src = g_input + (long)(bg0 + sb) * 512 * 9;
    float a = L.b_in[sf];
#pragma unroll
    for (int f = 0; f < 9; ++f) a = fmaf(src[f], L.w_in[f * 9 + sf], a);
    L.s_buf[0][sb][sf] = fmaxf(a, 0.f);
  }
  __syncthreads();

  // ---- main recurrence: ONE barrier per step ----
  for (int t = 0; t < 576; ++t) {
    const int p = t & 1;
    if (tid < 400) {
      float z0 = bl, z1 = bl, z2 = bl, z3 = bl;
#pragma unroll
      for (int f = 0; f < 9; ++f) {
        z0 = fmaf(wx[f], L.s_buf[p][0][f], z0);
        z1 = fmaf(wx[f], L.s_buf[p][1][f], z1);
        z2 = fmaf(wx[f], L.s_buf[p][2][f], z2);
        z3 = fmaf(wx[f], L.s_buf[p][3][f], z3);
      }
#pragma unroll
      for (int k = 0; k < 100; k += 4) {
        const float4 h0 = *(const float4*)&L.h_buf[p][0][k];
        const float4 h1 = *(const float4*)&L.h_buf[p][1][k];
        const float4 h2 = *(const float4*)&L.h_buf[p][2][k];
        const float4 h3 = *(const float4*)&L.h_buf[p][3][k];
        z0 = fmaf(w[k], h0.x, z0); z0 = fmaf(w[k+1], h0.y, z0);
        z0 = fmaf(w[k+2], h0.z, z0); z0 = fmaf(w[k+3], h0.w, z0);
        z1 = fmaf(w[k], h1.x, z1); z1 = fmaf(w[k+1], h1.y, z1);
        z1 = fmaf(w[k+2], h1.z, z1); z1 = fmaf(w[k+3], h1.w, z1);
        z2 = fmaf(w[k], h2.x, z2); z2 = fmaf(w[k+1], h2.y, z2);
        z2 = fmaf(w[k+2], h2.z, z2); z2 = fmaf(w[k+3], h2.w, z2);
        z3 = fmaf(w[k], h3.x, z3); z3 = fmaf(w[k+1], h3.y, z3);
        z3 = fmaf(w[k+2], h3.z, z3); z3 = fmaf(w[k+3], h3.w, z3);
      }
      // publish my gate's activation for all 4 batches: element (b, gate q)
      L.act[kcol][q]      = aa / (1.f + __expf(-bb * z0)) + cc;
      L.act[kcol][4 + q]  = aa / (1.f + __expf(-bb * z1)) + cc;
      L.act[kcol][8 + q]  = aa / (1.f + __expf(-bb * z2)) + cc;
      L.act[kcol][12 + q] = aa / (1.f + __expf(-bb * z3)) + cc;
      __builtin_amdgcn_wave_barrier();  // pin store->read order (same-wave quad exchange)
      // combine for (batch=q, k=kcol): gates i,f,g,o contiguous at [kcol][4q..4q+3]
      const float4 g4 = *(const float4*)&L.act[kcol][4 * q];
      c_state = fmaf(g4.y, c_state, g4.x * g4.z);
      const float th = 2.f / (1.f + __expf(-2.f * c_state)) - 1.f;
      L.h_buf[p ^ 1][q][kcol] = g4.w * th;
    } else if (tid < 436) {
      if (t > 0) {  // output for step t-1 (h[t-1] in h_buf[p])
        float lg = L.b_out[od];
#pragma unroll
        for (int k = 0; k < 100; k += 4) {
          const float4 hv = *(const float4*)&L.h_buf[p][eb][k];
          const float4 wv = *(const float4*)&L.woutT[od][k];
          lg = fmaf(wv.x, hv.x, lg); lg = fmaf(wv.y, hv.y, lg);
          lg = fmaf(wv.z, hv.z, lg); lg = fmaf(wv.w, hv.w, lg);
        }
        const int lane0 = 16 + eb * 9;
        float m = lg;
#pragma unroll
        for (int j = 0; j < 9; ++j) m = fmaxf(m, __shfl(lg, lane0 + j, 64));
        const float e = __expf(lg - m);
        float ssum = 0.f;
#pragma unroll
        for (int j = 0; j < 9; ++j) ssum += __shfl(e, lane0 + j, 64);
        g_out[((long)(bg0 + eb) * 576 + (t - 1)) * 9 + od] = e / ssum;
      }
    } else if (tid >= 448 && tid < 484) {
      const int tt = t + 1;
      if (tt < 576) {
        const float* src; const float* wm; const float* bm;
        if (tt < 512) {
          src = g_input + ((long)(bg0 + sb) * 512 + tt) * 9;
          wm = L.w_in;  bm = L.b_in;
        } else {
          src = g_task + ((long)(bg0 + sb) * 64 + (tt - 512)) * 9;
          wm = L.w_task; bm = L.b_task;
        }
        float a = bm[sf];
#pragma unroll
        for (int f = 0; f < 9; ++f) a = fmaf(src[f], wm[f * 9 + sf], a);
        L.s_buf[tt & 1][sb][sf] = fmaxf(a, 0.f);
      }
    }
    __syncthreads();
  }

  // ---- tail epilogue: output for t = 575 (h[575] in h_buf[0]) ----
  if (tid >= 400 && tid < 436) {
    float lg = L.b_out[od];
#pragma unroll
    for (int k = 0; k < 100; k += 4) {
      const float4 hv = *(const float4*)&L.h_buf[0][eb][k];
      const float4 wv = *(const float4*)&L.woutT[od][k];
      lg = fmaf(wv.x, hv.x, lg); lg = fmaf(wv.y, hv.y, lg);
      lg = fmaf(wv.z, hv.z, lg); lg = fmaf(wv.w, hv.w, lg);
    }
    const int lane0 = 16 + eb * 9;
    float m = lg;
#pragma unroll
    for (int j = 0; j < 9; ++j) m = fmaxf(m, __shfl(lg, lane0 + j, 64));
    const float e = __expf(lg - m);
    float ssum = 0.f;
#pragma unroll
    for (int j = 0; j < 9; ++j) ssum += __shfl(e, lane0 + j, 64);
    g_out[((long)(bg0 + eb) * 576 + 575) * 9 + od] = e / ssum;
  }
}

extern "C" void kernel_launch(void* const* d_in, const int* in_sizes, int n_in,
                              void* d_out, int out_size, void* d_ws, size_t ws_size,
                              hipStream_t stream) {
  const float* input  = (const float*)d_in[0];
  const float* task   = (const float*)d_in[1];
  const float* W_in   = (const float*)d_in[2];
  const float* b_in   = (const float*)d_in[3];
  const float* W_task = (const float*)d_in[4];
  const float* b_task = (const float*)d_in[5];
  const float* W_x    = (const float*)d_in[6];
  const float* W_h    = (const float*)d_in[7];
  const float* b_lstm = (const float*)d_in[8];
  const float* W_out  = (const float*)d_in[9];
  const float* b_out  = (const float*)d_in[10];
  float* out = (float*)d_out;

  lstm_fused<<<256, NTHR, 0, stream>>>(input, task, W_in, b_in, W_task, b_task,
                                       W_x, W_h, b_lstm, W_out, b_out, out);
}

// Round 3
// 1295.792 us; speedup vs baseline: 1.5397x; 1.3489x over previous
//
#include <hip/hip_runtime.h>

// Fused RNN: encoders + 576-step LSTM + projection + softmax.
// 256 blocks x 512 threads, 4 batches/block, 1 block/CU.
//
// Round-3 restructure (fix LDS-broadcast bound + VGPR spill):
//  - H padded 100->112. Dot threads = 448 (waves 0-6, no intra-wave divergence).
//    Thread (g = tid>>2 in [0,112), kq = tid&3) owns all 4 gate columns of hdim g
//    over k-quarter kq*28..kq*28+27: weights = 28 float4 = 112 VGPRs.
//  - Per step: 28 ds_read_b128 of h (4-address broadcast, bank-disjoint) + 448 FMA.
//    vs round-2's 100 b128/lane: 3.5x fewer LDS issues on the per-CU DS pipe.
//  - z partials reduced across the quad with 2-stage DPP butterfly (pure VALU).
//    Lane kq then does batch kq's activations + c/h update -> ds_write one float.
//    No act table, ONE barrier per step.
//  - Wave 7: lanes 0..35 epilogue (W_out in the SAME wreg union -> no reg doubling),
//    lanes 36..63 stage encoder output s[t+1].
//  - __launch_bounds__(512,2): pin 2 waves/EU (256-VGPR cap) to stop spill-chasing.

#define NTHR 512

struct __align__(16) SM {
  float4 h4[2][4][28];   // [phase][batch][k-chunk]  h (112 floats/batch, pads=0)
  float4 s4[2][4][4];    // [phase][batch][f-chunk]  encoded input (16 floats, pads=0)
  float w_in[81], w_task[81];
  float b_in[9], b_task[9];
};

__device__ __forceinline__ float quad_reduce(float v) {
  // 2-stage butterfly across the 4 lanes of a quad; all 4 end with the full sum.
  int a = __builtin_amdgcn_update_dpp(0, __float_as_int(v), 0xB1, 0xF, 0xF, true); // quad_perm(1,0,3,2)
  v += __int_as_float(a);
  int b = __builtin_amdgcn_update_dpp(0, __float_as_int(v), 0x4E, 0xF, 0xF, true); // quad_perm(2,3,0,1)
  v += __int_as_float(b);
  return v;
}

__device__ __forceinline__ float fast_sigmoid(float x) {
  return 1.f / (1.f + __expf(-x));
}
__device__ __forceinline__ float fast_tanh(float x) {
  return 2.f / (1.f + __expf(-2.f * x)) - 1.f;
}

__global__ __launch_bounds__(NTHR, 2)
void lstm_fused(const float* __restrict__ g_input,
                const float* __restrict__ g_task,
                const float* __restrict__ g_Win,
                const float* __restrict__ g_bin,
                const float* __restrict__ g_Wtask,
                const float* __restrict__ g_btask,
                const float* __restrict__ g_Wx,
                const float* __restrict__ g_Wh,
                const float* __restrict__ g_bl,
                const float* __restrict__ g_Wout,
                const float* __restrict__ g_bout,
                float* __restrict__ g_out)
{
  __shared__ SM L;
  const int tid = threadIdx.x;
  const int bg0 = blockIdx.x * 4;

  // ---- cooperative LDS fill ----
  for (int i = tid; i < 81; i += NTHR) { L.w_in[i] = g_Win[i]; L.w_task[i] = g_Wtask[i]; }
  if (tid < 9) { L.b_in[tid] = g_bin[tid]; L.b_task[tid] = g_btask[tid]; }
  for (int i = tid; i < 2 * 4 * 28 * 4; i += NTHR) ((float*)L.h4)[i] = 0.f;
  for (int i = tid; i < 2 * 4 * 4 * 4; i += NTHR)  ((float*)L.s4)[i] = 0.f;

  // ---- roles ----
  const int g  = tid >> 2;          // dot: hdim 0..111 (100..111 dummy)
  const int kq = tid & 3;           // dot: k-quarter / batch for update
  const int el = tid - 448;         // wave-7 lane
  const int eb = (el >= 0 && el < 36) ? el / 9 : 0;
  const int od = (el >= 0 && el < 36) ? el % 9 : 0;
  const int sl = tid - 484;         // staging lane 0..27

  // ---- weight-stationary registers (role union: dot=W_h slice, epi=W_out col) ----
  float4 wreg[28];
  float4 wx4[4];
  float  bias_r[4];
  if (tid < 448) {
    const bool cv = (g < 100);
#pragma unroll
    for (int gt = 0; gt < 4; ++gt) {
      const int col = gt * 100 + (cv ? g : 0);
#pragma unroll
      for (int jj = 0; jj < 7; ++jj) {
        const int k0 = kq * 28 + jj * 4;
        float4 v;
        v.x = (cv && k0 + 0 < 100) ? g_Wh[(k0 + 0) * 400 + col] : 0.f;
        v.y = (cv && k0 + 1 < 100) ? g_Wh[(k0 + 1) * 400 + col] : 0.f;
        v.z = (cv && k0 + 2 < 100) ? g_Wh[(k0 + 2) * 400 + col] : 0.f;
        v.w = (cv && k0 + 3 < 100) ? g_Wh[(k0 + 3) * 400 + col] : 0.f;
        wreg[gt * 7 + jj] = v;
      }
      float4 wv;
      const int f0 = kq * 4;
      wv.x = (cv && f0 + 0 < 9) ? g_Wx[(f0 + 0) * 400 + col] : 0.f;
      wv.y = (cv && f0 + 1 < 9) ? g_Wx[(f0 + 1) * 400 + col] : 0.f;
      wv.z = (cv && f0 + 2 < 9) ? g_Wx[(f0 + 2) * 400 + col] : 0.f;
      wv.w = (cv && f0 + 3 < 9) ? g_Wx[(f0 + 3) * 400 + col] : 0.f;
      wx4[gt] = wv;
      bias_r[gt] = cv ? g_bl[col] : 0.f;
    }
  } else if (el < 36) {
#pragma unroll
    for (int j = 0; j < 28; ++j) {
      const int k0 = 4 * j;
      float4 v;
      v.x = (k0 + 0 < 100) ? g_Wout[(k0 + 0) * 9 + od] : 0.f;
      v.y = (k0 + 1 < 100) ? g_Wout[(k0 + 1) * 9 + od] : 0.f;
      v.z = (k0 + 2 < 100) ? g_Wout[(k0 + 2) * 9 + od] : 0.f;
      v.w = (k0 + 3 < 100) ? g_Wout[(k0 + 3) * 9 + od] : 0.f;
      wreg[j] = v;
    }
    bias_r[0] = g_bout[od];
  }

  float c_state = 0.f;   // dot lanes: cell state for (batch kq, hdim g)

  __syncthreads();

  // ---- prologue: stage encoded s for t=0 (staging lanes) ----
  if (tid >= 484) {
#pragma unroll 1
    for (int pass = 0; pass < 2; ++pass) {
      const int j = sl + pass * 28;
      if (j < 36) {
        const int b = j / 9, f = j % 9;
        const float* src = g_input + (long)(bg0 + b) * 512 * 9;
        float a = L.b_in[f];
#pragma unroll
        for (int ff = 0; ff < 9; ++ff) a = fmaf(src[ff], L.w_in[ff * 9 + f], a);
        ((float*)&L.s4[0][b][0])[f] = fmaxf(a, 0.f);
      }
    }
  }
  __syncthreads();

  // ---- main recurrence: ONE barrier per step ----
  for (int t = 0; t < 576; ++t) {
    const int p = t & 1;
    if (tid < 448) {
      float z[4][4];
#pragma unroll
      for (int gt = 0; gt < 4; ++gt)
#pragma unroll
        for (int b = 0; b < 4; ++b) z[gt][b] = 0.f;

      // input-encoder contribution (features kq*4..kq*4+3, zero-padded)
#pragma unroll
      for (int b = 0; b < 4; ++b) {
        const float4 sv = L.s4[p][b][kq];
#pragma unroll
        for (int gt = 0; gt < 4; ++gt) {
          float a = wx4[gt].x * sv.x;
          a = fmaf(wx4[gt].y, sv.y, a);
          a = fmaf(wx4[gt].z, sv.z, a);
          a = fmaf(wx4[gt].w, sv.w, a);
          z[gt][b] += a;
        }
      }

      // recurrent dot: k-quarter kq, all 4 gates, all 4 batches
      const float4* hp = &L.h4[p][0][kq * 7];
#pragma unroll
      for (int j = 0; j < 7; ++j) {
        const float4 h0 = hp[j];
        const float4 h1 = hp[28 + j];
        const float4 h2 = hp[56 + j];
        const float4 h3 = hp[84 + j];
#pragma unroll
        for (int gt = 0; gt < 4; ++gt) {
          const float4 w = wreg[gt * 7 + j];
          z[gt][0] = fmaf(w.x, h0.x, z[gt][0]); z[gt][0] = fmaf(w.y, h0.y, z[gt][0]);
          z[gt][0] = fmaf(w.z, h0.z, z[gt][0]); z[gt][0] = fmaf(w.w, h0.w, z[gt][0]);
          z[gt][1] = fmaf(w.x, h1.x, z[gt][1]); z[gt][1] = fmaf(w.y, h1.y, z[gt][1]);
          z[gt][1] = fmaf(w.z, h1.z, z[gt][1]); z[gt][1] = fmaf(w.w, h1.w, z[gt][1]);
          z[gt][2] = fmaf(w.x, h2.x, z[gt][2]); z[gt][2] = fmaf(w.y, h2.y, z[gt][2]);
          z[gt][2] = fmaf(w.z, h2.z, z[gt][2]); z[gt][2] = fmaf(w.w, h2.w, z[gt][2]);
          z[gt][3] = fmaf(w.x, h3.x, z[gt][3]); z[gt][3] = fmaf(w.y, h3.y, z[gt][3]);
          z[gt][3] = fmaf(w.z, h3.z, z[gt][3]); z[gt][3] = fmaf(w.w, h3.w, z[gt][3]);
        }
      }

      // quad reduction (DPP butterfly) -> every lane has all 16 sums
#pragma unroll
      for (int gt = 0; gt < 4; ++gt)
#pragma unroll
        for (int b = 0; b < 4; ++b) z[gt][b] = quad_reduce(z[gt][b]);

      // lane kq handles batch kq
      float zz[4];
#pragma unroll
      for (int gt = 0; gt < 4; ++gt) {
        float r = (kq == 0) ? z[gt][0] : (kq == 1) ? z[gt][1] : (kq == 2) ? z[gt][2] : z[gt][3];
        zz[gt] = r + bias_r[gt];
      }
      const float gi = fast_sigmoid(zz[0]);
      const float gf = fast_sigmoid(zz[1]);
      const float gg = fast_tanh(zz[2]);
      const float go = fast_sigmoid(zz[3]);
      c_state = fmaf(gf, c_state, gi * gg);
      ((float*)&L.h4[p ^ 1][kq][0])[g] = go * fast_tanh(c_state);
    } else if (el < 36) {
      if (t > 0) {  // output for step t-1 (h[t-1] in h4[p])
        float lg = bias_r[0];
        const float4* hp = &L.h4[p][eb][0];
#pragma unroll
        for (int j = 0; j < 28; ++j) {
          const float4 hv = hp[j];
          const float4 wv = wreg[j];
          lg = fmaf(wv.x, hv.x, lg); lg = fmaf(wv.y, hv.y, lg);
          lg = fmaf(wv.z, hv.z, lg); lg = fmaf(wv.w, hv.w, lg);
        }
        const int lane0 = eb * 9;
        float m = lg;
#pragma unroll
        for (int j = 0; j < 9; ++j) m = fmaxf(m, __shfl(lg, lane0 + j, 64));
        const float e = __expf(lg - m);
        float ssum = 0.f;
#pragma unroll
        for (int j = 0; j < 9; ++j) ssum += __shfl(e, lane0 + j, 64);
        g_out[((long)(bg0 + eb) * 576 + (t - 1)) * 9 + od] = e / ssum;
      }
    } else {
      const int tt = t + 1;
      if (tt < 576) {
#pragma unroll 1
        for (int pass = 0; pass < 2; ++pass) {
          const int j = sl + pass * 28;
          if (j < 36) {
            const int b = j / 9, f = j % 9;
            const float* src; const float* wm; const float* bm;
            if (tt < 512) {
              src = g_input + ((long)(bg0 + b) * 512 + tt) * 9;
              wm = L.w_in;  bm = L.b_in;
            } else {
              src = g_task + ((long)(bg0 + b) * 64 + (tt - 512)) * 9;
              wm = L.w_task; bm = L.b_task;
            }
            float a = bm[f];
#pragma unroll
            for (int ff = 0; ff < 9; ++ff) a = fmaf(src[ff], wm[ff * 9 + f], a);
            ((float*)&L.s4[tt & 1][b][0])[f] = fmaxf(a, 0.f);
          }
        }
      }
    }
    __syncthreads();
  }

  // ---- tail: output for t=575 (h[575] in h4[0]) ----
  if (tid >= 448 && el < 36) {
    float lg = bias_r[0];
    const float4* hp = &L.h4[0][eb][0];
#pragma unroll
    for (int j = 0; j < 28; ++j) {
      const float4 hv = hp[j];
      const float4 wv = wreg[j];
      lg = fmaf(wv.x, hv.x, lg); lg = fmaf(wv.y, hv.y, lg);
      lg = fmaf(wv.z, hv.z, lg); lg = fmaf(wv.w, hv.w, lg);
    }
    const int lane0 = eb * 9;
    float m = lg;
#pragma unroll
    for (int j = 0; j < 9; ++j) m = fmaxf(m, __shfl(lg, lane0 + j, 64));
    const float e = __expf(lg - m);
    float ssum = 0.f;
#pragma unroll
    for (int j = 0; j < 9; ++j) ssum += __shfl(e, lane0 + j, 64);
    g_out[((long)(bg0 + eb) * 576 + 575) * 9 + od] = e / ssum;
  }
}

extern "C" void kernel_launch(void* const* d_in, const int* in_sizes, int n_in,
                              void* d_out, int out_size, void* d_ws, size_t ws_size,
                              hipStream_t stream) {
  const float* input  = (const float*)d_in[0];
  const float* task   = (const float*)d_in[1];
  const float* W_in   = (const float*)d_in[2];
  const float* b_in   = (const float*)d_in[3];
  const float* W_task = (const float*)d_in[4];
  const float* b_task = (const float*)d_in[5];
  const float* W_x    = (const float*)d_in[6];
  const float* W_h    = (const float*)d_in[7];
  const float* b_lstm = (const float*)d_in[8];
  const float* W_out  = (const float*)d_in[9];
  const float* b_out  = (const float*)d_in[10];
  float* out = (float*)d_out;

  lstm_fused<<<256, NTHR, 0, stream>>>(input, task, W_in, b_in, W_task, b_task,
                                       W_x, W_h, b_lstm, W_out, b_out, out);
}

// Round 4
// 923.456 us; speedup vs baseline: 2.1605x; 1.4032x over previous
//
#include <hip/hip_runtime.h>

// Fused RNN: encoders + 576-step LSTM + projection + softmax.
// 256 blocks x 512 threads, 4 batches/block, 1 block/CU.
//
// Round-4:
//  - Fused state vector y = [h(100), s(9), 1, 0, 0] (112 floats/batch):
//    encoder contribution + b_lstm become rows 100..109 of the weight matrix.
//    The z computation is ONE uniform 28-float4 FMA loop (no encoder block, no bias adds).
//  - v_rcp_f32 (__builtin_amdgcn_rcpf) replaces IEEE fp32 division in all
//    sigmoid/tanh/softmax (saves ~10 insts per division).
//  - amdgpu_agpr_alloc(0) (guarded): forbid AGPR allocation so the ~155 live
//    regs (112 weight floats + 16 acc + temps) stay in arch VGPRs (256 budget
//    at 2 waves/SIMD).  Round-3 counters showed VGPR_Count=100 -> AGPR split
//    inflated VALU issue ~2.2x over the hand count.

#define NTHR 512

#if defined(__has_attribute)
#if __has_attribute(amdgpu_agpr_alloc)
#define AGPR_HINT __attribute__((amdgpu_agpr_alloc(0)))
#else
#define AGPR_HINT
#endif
#else
#define AGPR_HINT
#endif

struct __align__(16) SM {
  float4 y4[2][4][28];   // [phase][batch][chunk]  y = [h(100), s(9), 1.0, 0, 0]
  float w_in[81], w_task[81];
  float b_in[9], b_task[9];
};

__device__ __forceinline__ float quad_reduce(float v) {
  int a = __builtin_amdgcn_update_dpp(0, __float_as_int(v), 0xB1, 0xF, 0xF, true); // quad_perm(1,0,3,2)
  v += __int_as_float(a);
  int b = __builtin_amdgcn_update_dpp(0, __float_as_int(v), 0x4E, 0xF, 0xF, true); // quad_perm(2,3,0,1)
  v += __int_as_float(b);
  return v;
}

__device__ __forceinline__ float fast_sigmoid(float x) {
  return __builtin_amdgcn_rcpf(1.f + __expf(-x));
}
__device__ __forceinline__ float fast_tanh(float x) {
  return fmaf(2.f, __builtin_amdgcn_rcpf(1.f + __expf(-2.f * x)), -1.f);
}

// W~ row k of column col: k<100 -> W_h, 100..108 -> W_x, 109 -> b_lstm, else 0.
__device__ __forceinline__ float wload(int k, int col,
                                       const float* __restrict__ Wh,
                                       const float* __restrict__ Wx,
                                       const float* __restrict__ bl) {
  if (k < 100)  return Wh[k * 400 + col];
  if (k < 109)  return Wx[(k - 100) * 400 + col];
  if (k == 109) return bl[col];
  return 0.f;
}

__global__ __launch_bounds__(NTHR, 2) AGPR_HINT
void lstm_fused(const float* __restrict__ g_input,
                const float* __restrict__ g_task,
                const float* __restrict__ g_Win,
                const float* __restrict__ g_bin,
                const float* __restrict__ g_Wtask,
                const float* __restrict__ g_btask,
                const float* __restrict__ g_Wx,
                const float* __restrict__ g_Wh,
                const float* __restrict__ g_bl,
                const float* __restrict__ g_Wout,
                const float* __restrict__ g_bout,
                float* __restrict__ g_out)
{
  __shared__ SM L;
  const int tid = threadIdx.x;
  const int bg0 = blockIdx.x * 4;

  // ---- cooperative LDS fill: y = 0 except y[109] = 1.0 (bias slot) ----
  for (int i = tid; i < 2 * 4 * 28 * 4; i += NTHR)
    ((float*)L.y4)[i] = ((i % 112) == 109) ? 1.f : 0.f;
  for (int i = tid; i < 81; i += NTHR) { L.w_in[i] = g_Win[i]; L.w_task[i] = g_Wtask[i]; }
  if (tid < 9) { L.b_in[tid] = g_bin[tid]; L.b_task[tid] = g_btask[tid]; }

  // ---- roles ----
  const int g  = tid >> 2;          // dot: hdim 0..111 (100..111 dummy)
  const int kq = tid & 3;           // dot: k-quarter; also batch for c/h update
  const int el = tid - 448;         // wave-7 lane
  const int eb = (el >= 0 && el < 36) ? el / 9 : 0;
  const int od = (el >= 0 && el < 36) ? el % 9 : 0;
  const int sl = tid - 484;         // staging lane 0..27

  // ---- weight-stationary registers (dot: 28 x float4 W~ slice; epi: W_out col) ----
  float4 wreg[28];
  float  breg = 0.f;
  if (tid < 448) {
    const bool cv = (g < 100);
    const int gcol = cv ? g : 0;
#pragma unroll
    for (int gt = 0; gt < 4; ++gt) {
      const int col = gt * 100 + gcol;
#pragma unroll
      for (int jj = 0; jj < 7; ++jj) {
        const int k0 = kq * 28 + jj * 4;
        float4 v;
        v.x = cv ? wload(k0 + 0, col, g_Wh, g_Wx, g_bl) : 0.f;
        v.y = cv ? wload(k0 + 1, col, g_Wh, g_Wx, g_bl) : 0.f;
        v.z = cv ? wload(k0 + 2, col, g_Wh, g_Wx, g_bl) : 0.f;
        v.w = cv ? wload(k0 + 3, col, g_Wh, g_Wx, g_bl) : 0.f;
        wreg[gt * 7 + jj] = v;
      }
    }
  } else if (el < 36) {
#pragma unroll
    for (int j = 0; j < 25; ++j) {
      const int k0 = 4 * j;
      float4 v;
      v.x = g_Wout[(k0 + 0) * 9 + od];
      v.y = g_Wout[(k0 + 1) * 9 + od];
      v.z = g_Wout[(k0 + 2) * 9 + od];
      v.w = g_Wout[(k0 + 3) * 9 + od];
      wreg[j] = v;
    }
    breg = g_bout[od];
  }

  float c_state = 0.f;   // dot lanes: cell state for (batch kq, hdim g)

  __syncthreads();

  // ---- prologue: stage encoded s for t=0 into phase 0 ----
  if (tid >= 484) {
#pragma unroll 1
    for (int pass = 0; pass < 2; ++pass) {
      const int j = sl + pass * 28;
      if (j < 36) {
        const int b = j / 9, f = j % 9;
        const float* src = g_input + (long)(bg0 + b) * 512 * 9;
        float a = L.b_in[f];
#pragma unroll
        for (int ff = 0; ff < 9; ++ff) a = fmaf(src[ff], L.w_in[ff * 9 + f], a);
        ((float*)&L.y4[0][b][0])[100 + f] = fmaxf(a, 0.f);
      }
    }
  }
  __syncthreads();

  // ---- main recurrence: ONE barrier per step ----
  for (int t = 0; t < 576; ++t) {
    const int p = t & 1;
    if (tid < 448) {
      float z[4][4];
#pragma unroll
      for (int gt = 0; gt < 4; ++gt)
#pragma unroll
        for (int b = 0; b < 4; ++b) z[gt][b] = 0.f;

      // z = W~^T y over k-quarter kq, all 4 gates, all 4 batches
      const float4* yp = &L.y4[p][0][kq * 7];
#pragma unroll
      for (int j = 0; j < 7; ++j) {
        const float4 h0 = yp[j];
        const float4 h1 = yp[28 + j];
        const float4 h2 = yp[56 + j];
        const float4 h3 = yp[84 + j];
#pragma unroll
        for (int gt = 0; gt < 4; ++gt) {
          const float4 w = wreg[gt * 7 + j];
          z[gt][0] = fmaf(w.x, h0.x, z[gt][0]); z[gt][0] = fmaf(w.y, h0.y, z[gt][0]);
          z[gt][0] = fmaf(w.z, h0.z, z[gt][0]); z[gt][0] = fmaf(w.w, h0.w, z[gt][0]);
          z[gt][1] = fmaf(w.x, h1.x, z[gt][1]); z[gt][1] = fmaf(w.y, h1.y, z[gt][1]);
          z[gt][1] = fmaf(w.z, h1.z, z[gt][1]); z[gt][1] = fmaf(w.w, h1.w, z[gt][1]);
          z[gt][2] = fmaf(w.x, h2.x, z[gt][2]); z[gt][2] = fmaf(w.y, h2.y, z[gt][2]);
          z[gt][2] = fmaf(w.z, h2.z, z[gt][2]); z[gt][2] = fmaf(w.w, h2.w, z[gt][2]);
          z[gt][3] = fmaf(w.x, h3.x, z[gt][3]); z[gt][3] = fmaf(w.y, h3.y, z[gt][3]);
          z[gt][3] = fmaf(w.z, h3.z, z[gt][3]); z[gt][3] = fmaf(w.w, h3.w, z[gt][3]);
        }
      }

      // quad reduction (DPP butterfly) -> all lanes hold all 16 sums
#pragma unroll
      for (int gt = 0; gt < 4; ++gt)
#pragma unroll
        for (int b = 0; b < 4; ++b) z[gt][b] = quad_reduce(z[gt][b]);

      // lane kq handles batch kq (bias already folded via y[109]=1)
      const bool k1 = kq & 1, k2 = kq & 2;
      float zz[4];
#pragma unroll
      for (int gt = 0; gt < 4; ++gt)
        zz[gt] = k2 ? (k1 ? z[gt][3] : z[gt][2]) : (k1 ? z[gt][1] : z[gt][0]);

      const float gi = fast_sigmoid(zz[0]);
      const float gf = fast_sigmoid(zz[1]);
      const float gg = fast_tanh(zz[2]);
      const float go = fast_sigmoid(zz[3]);
      c_state = fmaf(gf, c_state, gi * gg);
      if (g < 100)
        ((float*)&L.y4[p ^ 1][kq][0])[g] = go * fast_tanh(c_state);
    } else if (el < 36) {
      if (t > 0) {  // output for step t-1 (h[t-1] in y4[p][.][0..24])
        float lg = breg;
        const float4* hp = &L.y4[p][eb][0];
#pragma unroll
        for (int j = 0; j < 25; ++j) {
          const float4 hv = hp[j];
          const float4 wv = wreg[j];
          lg = fmaf(wv.x, hv.x, lg); lg = fmaf(wv.y, hv.y, lg);
          lg = fmaf(wv.z, hv.z, lg); lg = fmaf(wv.w, hv.w, lg);
        }
        const int lane0 = eb * 9;
        float m = lg;
#pragma unroll
        for (int j = 0; j < 9; ++j) m = fmaxf(m, __shfl(lg, lane0 + j, 64));
        const float e = __expf(lg - m);
        float ssum = 0.f;
#pragma unroll
        for (int j = 0; j < 9; ++j) ssum += __shfl(e, lane0 + j, 64);
        g_out[((long)(bg0 + eb) * 576 + (t - 1)) * 9 + od] = e * __builtin_amdgcn_rcpf(ssum);
      }
    } else {
      const int tt = t + 1;
      if (tt < 576) {  // stage s[t+1] into phase p^1, slots 100..108
#pragma unroll 1
        for (int pass = 0; pass < 2; ++pass) {
          const int j = sl + pass * 28;
          if (j < 36) {
            const int b = j / 9, f = j % 9;
            const float* src; const float* wm; const float* bm;
            if (tt < 512) {
              src = g_input + ((long)(bg0 + b) * 512 + tt) * 9;
              wm = L.w_in;  bm = L.b_in;
            } else {
              src = g_task + ((long)(bg0 + b) * 64 + (tt - 512)) * 9;
              wm = L.w_task; bm = L.b_task;
            }
            float a = bm[f];
#pragma unroll
            for (int ff = 0; ff < 9; ++ff) a = fmaf(src[ff], wm[ff * 9 + f], a);
            ((float*)&L.y4[tt & 1][b][0])[100 + f] = fmaxf(a, 0.f);
          }
        }
      }
    }
    __syncthreads();
  }

  // ---- tail: output for t=575 (h[575] in y4[0]) ----
  if (tid >= 448 && el < 36) {
    float lg = breg;
    const float4* hp = &L.y4[0][eb][0];
#pragma unroll
    for (int j = 0; j < 25; ++j) {
      const float4 hv = hp[j];
      const float4 wv = wreg[j];
      lg = fmaf(wv.x, hv.x, lg); lg = fmaf(wv.y, hv.y, lg);
      lg = fmaf(wv.z, hv.z, lg); lg = fmaf(wv.w, hv.w, lg);
    }
    const int lane0 = eb * 9;
    float m = lg;
#pragma unroll
    for (int j = 0; j < 9; ++j) m = fmaxf(m, __shfl(lg, lane0 + j, 64));
    const float e = __expf(lg - m);
    float ssum = 0.f;
#pragma unroll
    for (int j = 0; j < 9; ++j) ssum += __shfl(e, lane0 + j, 64);
    g_out[((long)(bg0 + eb) * 576 + 575) * 9 + od] = e * __builtin_amdgcn_rcpf(ssum);
  }
}

extern "C" void kernel_launch(void* const* d_in, const int* in_sizes, int n_in,
                              void* d_out, int out_size, void* d_ws, size_t ws_size,
                              hipStream_t stream) {
  const float* input  = (const float*)d_in[0];
  const float* task   = (const float*)d_in[1];
  const float* W_in   = (const float*)d_in[2];
  const float* b_in   = (const float*)d_in[3];
  const float* W_task = (const float*)d_in[4];
  const float* b_task = (const float*)d_in[5];
  const float* W_x    = (const float*)d_in[6];
  const float* W_h    = (const float*)d_in[7];
  const float* b_lstm = (const float*)d_in[8];
  const float* W_out  = (const float*)d_in[9];
  const float* b_out  = (const float*)d_in[10];
  float* out = (float*)d_out;

  lstm_fused<<<256, NTHR, 0, stream>>>(input, task, W_in, b_in, W_task, b_task,
                                       W_x, W_h, b_lstm, W_out, b_out, out);
}

// Round 5
// 871.901 us; speedup vs baseline: 2.2883x; 1.0591x over previous
//
#include <hip/hip_runtime.h>

// Fused RNN: encoders + 576-step LSTM + projection + softmax.
// 256 blocks x 512 threads, 4 batches/block, 1 block/CU.
//
// Round-5: f16 state + v_dot2_f32_f16 (full-rate dual MAC, fp32 accumulate).
//  - y = [h(100), s(9), 1, 0, 0] stored in LDS as _Float16[112] per batch/phase.
//    DS per thread-step: 4 batches x (3 ds_read_b128 + 1 ds_read_b64) = 16 insts
//    (vs 28 b128 fp32).  Weights as 56 half2 regs (vs 112 fp32) -> no AGPR split.
//  - 448 fp32 FMA -> 224 v_dot2_f32_f16 per thread-step; c_state & all
//    accumulation stay fp32.
//  - Ring reduce-scatter across the quad (batch-rotated partials, DPP
//    quad_perm(1,2,3,0)): 24 insts vs 64-inst butterfly; no lane-select.

#define NTHR 512

typedef _Float16 h2  __attribute__((ext_vector_type(2)));
typedef _Float16 h4v __attribute__((ext_vector_type(4)));
typedef _Float16 h8v __attribute__((ext_vector_type(8)));

struct __align__(16) SM {
  _Float16 Y[2][4][112];   // [phase][batch][k]: h(0..99), s(100..108), 1.0 (109), 0, 0
  float w_in[81], w_task[81];
  float b_in[9], b_task[9];
};

__device__ __forceinline__ float dot2(h2 a, h2 b, float c) {
#if defined(__has_builtin)
#if __has_builtin(__builtin_amdgcn_fdot2)
  return __builtin_amdgcn_fdot2(a, b, c, false);
#else
  return fmaf((float)a.x, (float)b.x, fmaf((float)a.y, (float)b.y, c));
#endif
#else
  return fmaf((float)a.x, (float)b.x, fmaf((float)a.y, (float)b.y, c));
#endif
}

__device__ __forceinline__ float dpp_rot(float v) {
  // lane i receives lane (i+1)&3 of its quad: quad_perm(1,2,3,0) = 0x39
  return __int_as_float(__builtin_amdgcn_update_dpp(0, __float_as_int(v), 0x39, 0xF, 0xF, true));
}

__device__ __forceinline__ float fast_sigmoid(float x) {
  return __builtin_amdgcn_rcpf(1.f + __expf(-x));
}
__device__ __forceinline__ float fast_tanh(float x) {
  return fmaf(2.f, __builtin_amdgcn_rcpf(1.f + __expf(-2.f * x)), -1.f);
}

// W~ row k of column col: k<100 -> W_h, 100..108 -> W_x, 109 -> b_lstm, else 0.
__device__ __forceinline__ float wld(int k, int col,
                                     const float* __restrict__ Wh,
                                     const float* __restrict__ Wx,
                                     const float* __restrict__ bl) {
  if (k < 100)  return Wh[k * 400 + col];
  if (k < 109)  return Wx[(k - 100) * 400 + col];
  if (k == 109) return bl[col];
  return 0.f;
}

__global__ __launch_bounds__(NTHR, 2)
void lstm_fused(const float* __restrict__ g_input,
                const float* __restrict__ g_task,
                const float* __restrict__ g_Win,
                const float* __restrict__ g_bin,
                const float* __restrict__ g_Wtask,
                const float* __restrict__ g_btask,
                const float* __restrict__ g_Wx,
                const float* __restrict__ g_Wh,
                const float* __restrict__ g_bl,
                const float* __restrict__ g_Wout,
                const float* __restrict__ g_bout,
                float* __restrict__ g_out)
{
  __shared__ SM L;
  const int tid = threadIdx.x;
  const int bg0 = blockIdx.x * 4;

  // ---- cooperative LDS fill: Y = 0 except slot 109 = 1.0 (bias) ----
  for (int i = tid; i < 2 * 4 * 112; i += NTHR)
    ((_Float16*)L.Y)[i] = ((i % 112) == 109) ? (_Float16)1.f : (_Float16)0.f;
  for (int i = tid; i < 81; i += NTHR) { L.w_in[i] = g_Win[i]; L.w_task[i] = g_Wtask[i]; }
  if (tid < 9) { L.b_in[tid] = g_bin[tid]; L.b_task[tid] = g_btask[tid]; }

  // ---- roles ----
  const int g  = tid >> 2;          // dot: hdim 0..111 (100..111 dummy)
  const int kq = tid & 3;           // dot: k-quarter; also my batch for c/h update
  const int el = tid - 448;         // wave-7 lane
  const int eb = (el >= 0 && el < 36) ? el / 9 : 0;
  const int od = (el >= 0 && el < 36) ? el % 9 : 0;
  const int sl = tid - 484;         // staging lane 0..27

  // per-lane DS layout of my k-quarter (28 halves = 56 B, 3 b128 + 1 b64):
  //  even kq: b128 @ qb, qb+16, qb+32 ; b64 @ qb+48
  //  odd  kq: b64  @ qb ; b128 @ qb+8, qb+24, qb+40
  const int qb  = kq * 56;
  const int odd = kq & 1;
  const int oA  = odd ? qb + 8 : qb;
  const int oB  = oA + 16;
  const int oC  = oA + 32;
  const int oD  = odd ? qb : qb + 48;

  // ---- weight-stationary half2 registers (union: dot = W~ slice, epi = W_out col) ----
  h2 wv[56];
  float breg = 0.f;
  if (tid < 448) {
    const bool cv = (g < 100);
    const int gcol = cv ? g : 0;
#pragma unroll
    for (int gt = 0; gt < 4; ++gt) {
      const int col = gt * 100 + gcol;
#pragma unroll
      for (int s = 0; s < 14; ++s) {
        // consumption slot s -> k-pair index within my quarter (matches read order)
        const int kp = odd ? ((s < 12) ? s + 2 : s - 12) : s;
        const int k0 = kq * 28 + 2 * kp;
        const float w0 = cv ? wld(k0 + 0, col, g_Wh, g_Wx, g_bl) : 0.f;
        const float w1 = cv ? wld(k0 + 1, col, g_Wh, g_Wx, g_bl) : 0.f;
        h2 h; h.x = (_Float16)w0; h.y = (_Float16)w1;
        wv[gt * 14 + s] = h;
      }
    }
  } else if (el < 36) {
#pragma unroll
    for (int j = 0; j < 56; ++j) {
      const int k0 = 2 * j;
      const float w0 = (k0 + 0 < 100) ? g_Wout[(k0 + 0) * 9 + od] : 0.f;
      const float w1 = (k0 + 1 < 100) ? g_Wout[(k0 + 1) * 9 + od] : 0.f;
      h2 h; h.x = (_Float16)w0; h.y = (_Float16)w1;
      wv[j] = h;
    }
    breg = g_bout[od];
  }

  float c_state = 0.f;   // dot lanes: cell state for (batch kq, hdim g)

  __syncthreads();

  // ---- prologue: stage encoded s for t=0 into phase 0 ----
  if (tid >= 484) {
#pragma unroll 1
    for (int pass = 0; pass < 2; ++pass) {
      const int j = sl + pass * 28;
      if (j < 36) {
        const int b = j / 9, f = j % 9;
        const float* src = g_input + (long)(bg0 + b) * 512 * 9;
        float a = L.b_in[f];
#pragma unroll
        for (int ff = 0; ff < 9; ++ff) a = fmaf(src[ff], L.w_in[ff * 9 + f], a);
        L.Y[0][b][100 + f] = (_Float16)fmaxf(a, 0.f);
      }
    }
  }
  __syncthreads();

  // ---- main recurrence: ONE barrier per step ----
  for (int t = 0; t < 576; ++t) {
    const int p = t & 1;
    if (tid < 448) {
      // load y pairs for all 4 batches, batch-rotated: slot r = batch (kq+r)&3
      h2 yp[4][14];
#pragma unroll
      for (int r = 0; r < 4; ++r) {
        const int br = (kq + r) & 3;
        const char* yr = (const char*)&L.Y[p][br][0];
        const h8v A = *(const h8v*)(yr + oA);
        const h8v B = *(const h8v*)(yr + oB);
        const h8v C = *(const h8v*)(yr + oC);
        const h4v D = *(const h4v*)(yr + oD);
        yp[r][0]  = __builtin_shufflevector(A, A, 0, 1);
        yp[r][1]  = __builtin_shufflevector(A, A, 2, 3);
        yp[r][2]  = __builtin_shufflevector(A, A, 4, 5);
        yp[r][3]  = __builtin_shufflevector(A, A, 6, 7);
        yp[r][4]  = __builtin_shufflevector(B, B, 0, 1);
        yp[r][5]  = __builtin_shufflevector(B, B, 2, 3);
        yp[r][6]  = __builtin_shufflevector(B, B, 4, 5);
        yp[r][7]  = __builtin_shufflevector(B, B, 6, 7);
        yp[r][8]  = __builtin_shufflevector(C, C, 0, 1);
        yp[r][9]  = __builtin_shufflevector(C, C, 2, 3);
        yp[r][10] = __builtin_shufflevector(C, C, 4, 5);
        yp[r][11] = __builtin_shufflevector(C, C, 6, 7);
        yp[r][12] = __builtin_shufflevector(D, D, 0, 1);
        yp[r][13] = __builtin_shufflevector(D, D, 2, 3);
      }

      // 224 dot2: z[gt][r] = partial (my k-quarter) for gate gt, batch (kq+r)&3
      float z[4][4];
#pragma unroll
      for (int gt = 0; gt < 4; ++gt) {
#pragma unroll
        for (int r = 0; r < 4; ++r) {
          float a = 0.f;
#pragma unroll
          for (int s = 0; s < 14; ++s) a = dot2(wv[gt * 14 + s], yp[r][s], a);
          z[gt][r] = a;
        }
      }

      // ring reduce-scatter across the quad: lane kq ends with full z for batch kq
      float zz[4];
#pragma unroll
      for (int gt = 0; gt < 4; ++gt) {
        float A = z[gt][1];
        A = dpp_rot(A) + z[gt][2];
        A = dpp_rot(A) + z[gt][3];
        A = dpp_rot(A) + z[gt][0];
        zz[gt] = A;
      }

      const float gi = fast_sigmoid(zz[0]);
      const float gf = fast_sigmoid(zz[1]);
      const float gg = fast_tanh(zz[2]);
      const float go = fast_sigmoid(zz[3]);
      c_state = fmaf(gf, c_state, gi * gg);
      const float h = go * fast_tanh(c_state);
      if (g < 100)
        L.Y[p ^ 1][kq][g] = (_Float16)h;
    } else if (el < 36) {
      if (t > 0) {  // output for step t-1 (h[t-1] in Y[p])
        float lg = breg;
        const char* yr = (const char*)&L.Y[p][eb][0];
#pragma unroll
        for (int j = 0; j < 14; ++j) {
          const h8v v = *(const h8v*)(yr + 16 * j);
          lg = dot2(wv[4 * j + 0], __builtin_shufflevector(v, v, 0, 1), lg);
          lg = dot2(wv[4 * j + 1], __builtin_shufflevector(v, v, 2, 3), lg);
          lg = dot2(wv[4 * j + 2], __builtin_shufflevector(v, v, 4, 5), lg);
          lg = dot2(wv[4 * j + 3], __builtin_shufflevector(v, v, 6, 7), lg);
        }
        const int lane0 = eb * 9;
        float m = lg;
#pragma unroll
        for (int j = 0; j < 9; ++j) m = fmaxf(m, __shfl(lg, lane0 + j, 64));
        const float e = __expf(lg - m);
        float ssum = 0.f;
#pragma unroll
        for (int j = 0; j < 9; ++j) ssum += __shfl(e, lane0 + j, 64);
        g_out[((long)(bg0 + eb) * 576 + (t - 1)) * 9 + od] = e * __builtin_amdgcn_rcpf(ssum);
      }
    } else {
      const int tt = t + 1;
      if (tt < 576) {  // stage s[t+1] into phase p^1, slots 100..108
#pragma unroll 1
        for (int pass = 0; pass < 2; ++pass) {
          const int j = sl + pass * 28;
          if (j < 36) {
            const int b = j / 9, f = j % 9;
            const float* src; const float* wm; const float* bm;
            if (tt < 512) {
              src = g_input + ((long)(bg0 + b) * 512 + tt) * 9;
              wm = L.w_in;  bm = L.b_in;
            } else {
              src = g_task + ((long)(bg0 + b) * 64 + (tt - 512)) * 9;
              wm = L.w_task; bm = L.b_task;
            }
            float a = bm[f];
#pragma unroll
            for (int ff = 0; ff < 9; ++ff) a = fmaf(src[ff], wm[ff * 9 + f], a);
            L.Y[tt & 1][b][100 + f] = (_Float16)fmaxf(a, 0.f);
          }
        }
      }
    }
    __syncthreads();
  }

  // ---- tail: output for t=575 (h[575] in Y[0]) ----
  if (tid >= 448 && el < 36) {
    float lg = breg;
    const char* yr = (const char*)&L.Y[0][eb][0];
#pragma unroll
    for (int j = 0; j < 14; ++j) {
      const h8v v = *(const h8v*)(yr + 16 * j);
      lg = dot2(wv[4 * j + 0], __builtin_shufflevector(v, v, 0, 1), lg);
      lg = dot2(wv[4 * j + 1], __builtin_shufflevector(v, v, 2, 3), lg);
      lg = dot2(wv[4 * j + 2], __builtin_shufflevector(v, v, 4, 5), lg);
      lg = dot2(wv[4 * j + 3], __builtin_shufflevector(v, v, 6, 7), lg);
    }
    const int lane0 = eb * 9;
    float m = lg;
#pragma unroll
    for (int j = 0; j < 9; ++j) m = fmaxf(m, __shfl(lg, lane0 + j, 64));
    const float e = __expf(lg - m);
    float ssum = 0.f;
#pragma unroll
    for (int j = 0; j < 9; ++j) ssum += __shfl(e, lane0 + j, 64);
    g_out[((long)(bg0 + eb) * 576 + 575) * 9 + od] = e * __builtin_amdgcn_rcpf(ssum);
  }
}

extern "C" void kernel_launch(void* const* d_in, const int* in_sizes, int n_in,
                              void* d_out, int out_size, void* d_ws, size_t ws_size,
                              hipStream_t stream) {
  const float* input  = (const float*)d_in[0];
  const float* task   = (const float*)d_in[1];
  const float* W_in   = (const float*)d_in[2];
  const float* b_in   = (const float*)d_in[3];
  const float* W_task = (const float*)d_in[4];
  const float* b_task = (const float*)d_in[5];
  const float* W_x    = (const float*)d_in[6];
  const float* W_h    = (const float*)d_in[7];
  const float* b_lstm = (const float*)d_in[8];
  const float* W_out  = (const float*)d_in[9];
  const float* b_out  = (const float*)d_in[10];
  float* out = (float*)d_out;

  lstm_fused<<<256, NTHR, 0, stream>>>(input, task, W_in, b_in, W_task, b_task,
                                       W_x, W_h, b_lstm, W_out, b_out, out);
}

// Round 6
// 787.573 us; speedup vs baseline: 2.5333x; 1.1071x over previous
//
#include <hip/hip_runtime.h>

// Fused RNN: encoders + 576-step LSTM + projection + softmax.
// 256 blocks x 512 threads, 4 batches/block, 1 block/CU.
//
// Round-6: recurrent GEMM on the MATRIX pipe (v_mfma_f32_16x16x32_f16).
//  - Z[4,400] = y[4(16),112(128)] @ W~[128,400] as 25 N-tiles x 4 K-chunks
//    = 100 MFMA/step/block on waves 0..6 (B weight-stationary in frag regs).
//  - y (f16) in LDS rows of 272 B stride (16B-aligned, bank-spread); A-frag =
//    1 ds_read_b128 per K-chunk; D: batches live in regs 0..3 of lanes 0..15
//    -> ds_write_b128 per tile into Z[400][4] (fp32).
//  - Activation phase: 400 threads (g=tid>>2,b=tid&3), conflict-free Z reads,
//    fp32 gates + c_state in register, h -> f16 ds_write_b16.
//  - Two barriers/step; wave 7 = projection+softmax (phase 1) / encoder staging
//    (phase 2), as in round 5.

#define NTHR 512

typedef _Float16 half8 __attribute__((ext_vector_type(8)));
typedef _Float16 h2   __attribute__((ext_vector_type(2)));
typedef _Float16 h4v  __attribute__((ext_vector_type(4)));
typedef _Float16 h8v  __attribute__((ext_vector_type(8)));
typedef float    f32x4 __attribute__((ext_vector_type(4)));

struct __align__(16) SM {
  _Float16 Y[2][16][136];  // [phase][m(batch,4 used)][k]: h(0..99), s(100..108), 1(109), 0(110..135)
  float Z[400][4];         // [n][batch] raw gate pre-activations
  float w_in[81], w_task[81];
  float b_in[9], b_task[9];
};

__device__ __forceinline__ float dot2(h2 a, h2 b, float c) {
#if defined(__has_builtin)
#if __has_builtin(__builtin_amdgcn_fdot2)
  return __builtin_amdgcn_fdot2(a, b, c, false);
#else
  return fmaf((float)a.x, (float)b.x, fmaf((float)a.y, (float)b.y, c));
#endif
#else
  return fmaf((float)a.x, (float)b.x, fmaf((float)a.y, (float)b.y, c));
#endif
}

__device__ __forceinline__ float fast_sigmoid(float x) {
  return __builtin_amdgcn_rcpf(1.f + __expf(-x));
}
__device__ __forceinline__ float fast_tanh(float x) {
  return fmaf(2.f, __builtin_amdgcn_rcpf(1.f + __expf(-2.f * x)), -1.f);
}

// W~ row k of column n: k<100 -> W_h, 100..108 -> W_x, 109 -> b_lstm, else 0.
__device__ __forceinline__ float wld(int k, int n,
                                     const float* __restrict__ Wh,
                                     const float* __restrict__ Wx,
                                     const float* __restrict__ bl) {
  if (k < 100)  return Wh[k * 400 + n];
  if (k < 109)  return Wx[(k - 100) * 400 + n];
  if (k == 109) return bl[n];
  return 0.f;
}

__global__ __launch_bounds__(NTHR, 2)
void lstm_fused(const float* __restrict__ g_input,
                const float* __restrict__ g_task,
                const float* __restrict__ g_Win,
                const float* __restrict__ g_bin,
                const float* __restrict__ g_Wtask,
                const float* __restrict__ g_btask,
                const float* __restrict__ g_Wx,
                const float* __restrict__ g_Wh,
                const float* __restrict__ g_bl,
                const float* __restrict__ g_Wout,
                const float* __restrict__ g_bout,
                float* __restrict__ g_out)
{
  __shared__ SM L;
  const int tid  = threadIdx.x;
  const int bg0  = blockIdx.x * 4;
  const int wv   = tid >> 6;        // wave id 0..7
  const int lane = tid & 63;
  const int q    = lane >> 4;       // MFMA quad 0..3
  const int nl   = lane & 15;       // MFMA n-within-tile / m(batch) for A

  // ---- cooperative LDS fill: Y = 0 except k==109 -> 1.0 (bias slot) ----
  for (int i = tid; i < 2 * 16 * 136; i += NTHR)
    ((_Float16*)L.Y)[i] = ((i % 136) == 109) ? (_Float16)1.f : (_Float16)0.f;
  for (int i = tid; i < 81; i += NTHR) { L.w_in[i] = g_Win[i]; L.w_task[i] = g_Wtask[i]; }
  if (tid < 9) { L.b_in[tid] = g_bin[tid]; L.b_task[tid] = g_btask[tid]; }

  // ---- MFMA tile ownership (waves 0..6): 25 N-tiles, clamped duplicates benign ----
  const int tbase = (wv < 4) ? wv * 4 : 16 + 3 * (wv - 4);

  // ---- B-fragments: W~[128,400] f16, weight-stationary (waves 0..6) ----
  half8 Bf[4][4];   // [ti][kc]; lane holds B[k=32kc+8q+j][n=16*tile+nl]
  if (wv < 7) {
#pragma unroll
    for (int ti = 0; ti < 4; ++ti) {
      const int tile = min(tbase + ti, 24);
      const int n = tile * 16 + nl;
#pragma unroll
      for (int kc = 0; kc < 4; ++kc) {
#pragma unroll
        for (int j = 0; j < 8; ++j) {
          const int k = kc * 32 + q * 8 + j;
          Bf[ti][kc][j] = (_Float16)wld(k, n, g_Wh, g_Wx, g_bl);
        }
      }
    }
  }

  // ---- wave-7 roles: proj (lanes 0..35) / staging (lanes 36..63) ----
  const int el = tid - 448;                         // wave-7 lane
  const int eb = (el >= 0 && el < 36) ? el / 9 : 0;
  const int od = (el >= 0 && el < 36) ? el % 9 : 0;
  const int sl = tid - 484;                         // staging lane 0..27
  h2 wout[50];
  float breg = 0.f;
  if (wv == 7 && el < 36) {
#pragma unroll
    for (int j = 0; j < 50; ++j) {
      h2 h; h.x = (_Float16)g_Wout[(2 * j) * 9 + od];
      h.y = (_Float16)g_Wout[(2 * j + 1) * 9 + od];
      wout[j] = h;
    }
    breg = g_bout[od];
  }

  // ---- activation role: thread tid<400 owns (g = tid>>2, b = tid&3) ----
  const int ag = tid >> 2, ab = tid & 3;
  float c_state = 0.f;

  __syncthreads();

  // ---- prologue: stage encoded s_0 into Y[0] (wave-7 lanes 36..63) ----
  if (tid >= 484) {
#pragma unroll 1
    for (int pass = 0; pass < 2; ++pass) {
      const int j = sl + pass * 28;
      if (j < 36) {
        const int b = j / 9, f = j % 9;
        const float* src = g_input + (long)(bg0 + b) * 512 * 9;
        float a = L.b_in[f];
#pragma unroll
        for (int ff = 0; ff < 9; ++ff) a = fmaf(src[ff], L.w_in[ff * 9 + f], a);
        L.Y[0][b][100 + f] = (_Float16)fmaxf(a, 0.f);
      }
    }
  }
  __syncthreads();

  // ---- main recurrence: 2 barriers/step ----
  for (int t = 0; t < 576; ++t) {
    const int p = t & 1;
    // ---------- phase 1: MFMA -> Z  (waves 0..6) | projection (wave 7) ----------
    if (wv < 7) {
      half8 A[4];
#pragma unroll
      for (int kc = 0; kc < 4; ++kc)
        A[kc] = *(const half8*)&L.Y[p][nl][kc * 32 + q * 8];
      f32x4 acc[4];
#pragma unroll
      for (int ti = 0; ti < 4; ++ti) {
        acc[ti] = (f32x4)0.f;
#pragma unroll
        for (int kc = 0; kc < 4; ++kc)
          acc[ti] = __builtin_amdgcn_mfma_f32_16x16x32_f16(A[kc], Bf[ti][kc], acc[ti], 0, 0, 0);
      }
      if (lane < 16) {
#pragma unroll
        for (int ti = 0; ti < 4; ++ti) {
          const int tile = min(tbase + ti, 24);
          *(f32x4*)&L.Z[tile * 16 + nl][0] = acc[ti];   // regs 0..3 = batches 0..3
        }
      }
    } else if (el < 36) {
      if (t > 0) {  // projection + softmax for step t-1 (h[t-1] in Y[p])
        float lg = breg;
        const _Float16* yr = &L.Y[p][eb][0];
#pragma unroll
        for (int j = 0; j < 12; ++j) {
          const h8v v = *(const h8v*)(yr + 8 * j);
          lg = dot2(wout[4 * j + 0], __builtin_shufflevector(v, v, 0, 1), lg);
          lg = dot2(wout[4 * j + 1], __builtin_shufflevector(v, v, 2, 3), lg);
          lg = dot2(wout[4 * j + 2], __builtin_shufflevector(v, v, 4, 5), lg);
          lg = dot2(wout[4 * j + 3], __builtin_shufflevector(v, v, 6, 7), lg);
        }
        const h4v tail = *(const h4v*)(yr + 96);
        lg = dot2(wout[48], __builtin_shufflevector(tail, tail, 0, 1), lg);
        lg = dot2(wout[49], __builtin_shufflevector(tail, tail, 2, 3), lg);
        const int lane0 = eb * 9;
        float m = lg;
#pragma unroll
        for (int j = 0; j < 9; ++j) m = fmaxf(m, __shfl(lg, lane0 + j, 64));
        const float e = __expf(lg - m);
        float ssum = 0.f;
#pragma unroll
        for (int j = 0; j < 9; ++j) ssum += __shfl(e, lane0 + j, 64);
        g_out[((long)(bg0 + eb) * 576 + (t - 1)) * 9 + od] = e * __builtin_amdgcn_rcpf(ssum);
      }
    }
    __syncthreads();
    // ---------- phase 2: activations + h-write (tid<400) | staging (wave-7 hi) ----------
    if (tid < 400) {
      const float zi = L.Z[ag][ab];
      const float zf = L.Z[100 + ag][ab];
      const float zg = L.Z[200 + ag][ab];
      const float zo = L.Z[300 + ag][ab];
      const float gi = fast_sigmoid(zi);
      const float gf = fast_sigmoid(zf);
      const float gg = fast_tanh(zg);
      const float go = fast_sigmoid(zo);
      c_state = fmaf(gf, c_state, gi * gg);
      L.Y[p ^ 1][ab][ag] = (_Float16)(go * fast_tanh(c_state));
    } else if (tid >= 484) {
      const int tt = t + 1;
      if (tt < 576) {
#pragma unroll 1
        for (int pass = 0; pass < 2; ++pass) {
          const int j = sl + pass * 28;
          if (j < 36) {
            const int b = j / 9, f = j % 9;
            const float* src; const float* wm; const float* bm;
            if (tt < 512) {
              src = g_input + ((long)(bg0 + b) * 512 + tt) * 9;
              wm = L.w_in;  bm = L.b_in;
            } else {
              src = g_task + ((long)(bg0 + b) * 64 + (tt - 512)) * 9;
              wm = L.w_task; bm = L.b_task;
            }
            float a = bm[f];
#pragma unroll
            for (int ff = 0; ff < 9; ++ff) a = fmaf(src[ff], wm[ff * 9 + f], a);
            L.Y[tt & 1][b][100 + f] = (_Float16)fmaxf(a, 0.f);
          }
        }
      }
    }
    __syncthreads();
  }

  // ---- tail: projection for t=575 (h[575] in Y[0]) ----
  if (wv == 7 && el < 36) {
    float lg = breg;
    const _Float16* yr = &L.Y[0][eb][0];
#pragma unroll
    for (int j = 0; j < 12; ++j) {
      const h8v v = *(const h8v*)(yr + 8 * j);
      lg = dot2(wout[4 * j + 0], __builtin_shufflevector(v, v, 0, 1), lg);
      lg = dot2(wout[4 * j + 1], __builtin_shufflevector(v, v, 2, 3), lg);
      lg = dot2(wout[4 * j + 2], __builtin_shufflevector(v, v, 4, 5), lg);
      lg = dot2(wout[4 * j + 3], __builtin_shufflevector(v, v, 6, 7), lg);
    }
    const h4v tail = *(const h4v*)(yr + 96);
    lg = dot2(wout[48], __builtin_shufflevector(tail, tail, 0, 1), lg);
    lg = dot2(wout[49], __builtin_shufflevector(tail, tail, 2, 3), lg);
    const int lane0 = eb * 9;
    float m = lg;
#pragma unroll
    for (int j = 0; j < 9; ++j) m = fmaxf(m, __shfl(lg, lane0 + j, 64));
    const float e = __expf(lg - m);
    float ssum = 0.f;
#pragma unroll
    for (int j = 0; j < 9; ++j) ssum += __shfl(e, lane0 + j, 64);
    g_out[((long)(bg0 + eb) * 576 + 575) * 9 + od] = e * __builtin_amdgcn_rcpf(ssum);
  }
}

extern "C" void kernel_launch(void* const* d_in, const int* in_sizes, int n_in,
                              void* d_out, int out_size, void* d_ws, size_t ws_size,
                              hipStream_t stream) {
  const float* input  = (const float*)d_in[0];
  const float* task   = (const float*)d_in[1];
  const float* W_in   = (const float*)d_in[2];
  const float* b_in   = (const float*)d_in[3];
  const float* W_task = (const float*)d_in[4];
  const float* b_task = (const float*)d_in[5];
  const float* W_x    = (const float*)d_in[6];
  const float* W_h    = (const float*)d_in[7];
  const float* b_lstm = (const float*)d_in[8];
  const float* W_out  = (const float*)d_in[9];
  const float* b_out  = (const float*)d_in[10];
  float* out = (float*)d_out;

  lstm_fused<<<256, NTHR, 0, stream>>>(input, task, W_in, b_in, W_task, b_task,
                                       W_x, W_h, b_lstm, W_out, b_out, out);
}